// Round 2
// baseline (340.021 us; speedup 1.0000x reference)
//
#include <hip/hip_runtime.h>
#include <hip/hip_bf16.h>

typedef unsigned short u16;
typedef unsigned int u32;
typedef __attribute__((ext_vector_type(8))) short short8;
typedef __attribute__((ext_vector_type(4))) float floatx4;

#define MDIM 4096
#define NDIM 4096
#define KDIM 4096
#define BM 128
#define BN 128
#define BK 32

// ---------------- fp32 -> bf16 conversion, both matrices, one launch --------
// One float4 per lane (16B coalesced load, 8B coalesced store), branchless RNE.
__global__ __launch_bounds__(256) void cvt2_f32_bf16(const float* __restrict__ x,
                                                     const float* __restrict__ w,
                                                     u16* __restrict__ xa,
                                                     u16* __restrict__ wb) {
    const int half = gridDim.x >> 1;
    int b = blockIdx.x;
    const float* src = x;
    u16* dst = xa;
    if (b >= half) { src = w; dst = wb; b -= half; }
    const int i = b * 256 + threadIdx.x;           // float4 index
    float4 f = ((const float4*)src)[i];
    u32 ua = __float_as_uint(f.x), ub = __float_as_uint(f.y);
    u32 uc = __float_as_uint(f.z), ud = __float_as_uint(f.w);
    // round-to-nearest-even to bf16 (inputs are finite random normals)
    ushort4 o;
    o.x = (u16)((ua + 0x7fffu + ((ua >> 16) & 1u)) >> 16);
    o.y = (u16)((ub + 0x7fffu + ((ub >> 16) & 1u)) >> 16);
    o.z = (u16)((uc + 0x7fffu + ((uc >> 16) & 1u)) >> 16);
    o.w = (u16)((ud + 0x7fffu + ((ud >> 16) & 1u)) >> 16);
    ((ushort4*)dst)[i] = o;
}

// ---------------- bf16 GEMM, C = A * B^T + bias (m97 structure) ----------------
// XOR chunk swizzle: k-chunk q of row r lives at LDS chunk-slot q^(r&3).
// Staging thread t (row=t>>2, slot=t&3) therefore FETCHES global chunk
// (t&3)^(r&3) — still one 64B segment per 4 lanes. Fragment reads go
// 8-way -> 4-way bank conflict (rows r, r+4 still alias: 64B row stride).
typedef const __attribute__((address_space(1))) void* gas_ptr;
typedef __attribute__((address_space(3))) void* lds_ptr;

__global__ __launch_bounds__(256) void gemm_bt_bias(const u16* __restrict__ A,
                                                    const u16* __restrict__ B,
                                                    const float* __restrict__ bias,
                                                    float* __restrict__ C) {
    __shared__ u16 lA[BM * BK];  // 8 KiB
    __shared__ u16 lB[BN * BK];  // 8 KiB

    const int t = threadIdx.x;
    const int bm0 = blockIdx.y * BM;
    const int bn0 = blockIdx.x * BN;

    const int wave = t >> 6;
    const int lane = t & 63;
    const int wm = (wave & 1) * 64;
    const int wn = (wave >> 1) * 64;
    const int lr = lane & 15;          // m (A) / n (B) within 16
    const int q  = lane >> 4;          // k-quad 0..3
    const int kq_sw = (q ^ (lr & 3)) * 8;  // swizzled k-chunk offset (elements)

    floatx4 acc[4][4] = {};

    // staging: thread t -> row r=t>>2 (plus 64), fetches swizzled global chunk
    const int r = t >> 2;
    const int csw = ((t & 3) ^ (r & 3)) * 8;   // global k-chunk to fetch (elements)
    const u16* gA0 = A + (size_t)(bm0 + r) * KDIM + csw;
    const u16* gA1 = A + (size_t)(bm0 + 64 + r) * KDIM + csw;   // (r+64)&3 == r&3
    const u16* gB0 = B + (size_t)(bn0 + r) * KDIM + csw;
    const u16* gB1 = B + (size_t)(bn0 + 64 + r) * KDIM + csw;
    u16* lA0 = &lA[(size_t)t * 8];
    u16* lA1 = &lA[2048 + (size_t)t * 8];
    u16* lB0 = &lB[(size_t)t * 8];
    u16* lB1 = &lB[2048 + (size_t)t * 8];

    for (int k0 = 0; k0 < KDIM; k0 += BK) {
        __builtin_amdgcn_global_load_lds((gas_ptr)(gA0 + k0), (lds_ptr)lA0, 16, 0, 0);
        __builtin_amdgcn_global_load_lds((gas_ptr)(gA1 + k0), (lds_ptr)lA1, 16, 0, 0);
        __builtin_amdgcn_global_load_lds((gas_ptr)(gB0 + k0), (lds_ptr)lB0, 16, 0, 0);
        __builtin_amdgcn_global_load_lds((gas_ptr)(gB1 + k0), (lds_ptr)lB1, 16, 0, 0);
        __syncthreads();  // drains vmcnt before LDS reads

        short8 af[4], bfr[4];
#pragma unroll
        for (int i = 0; i < 4; ++i)
            af[i] = *(const short8*)&lA[(wm + i * 16 + lr) * BK + kq_sw];
#pragma unroll
        for (int j = 0; j < 4; ++j)
            bfr[j] = *(const short8*)&lB[(wn + j * 16 + lr) * BK + kq_sw];

#pragma unroll
        for (int i = 0; i < 4; ++i)
#pragma unroll
            for (int j = 0; j < 4; ++j)
                acc[i][j] = __builtin_amdgcn_mfma_f32_16x16x32_bf16(af[i], bfr[j], acc[i][j], 0, 0, 0);
        __syncthreads();  // protect LDS before next-iter staging
    }

    // epilogue: C/D layout col=lane&15, row=(lane>>4)*4+qq  [m89-verified]
#pragma unroll
    for (int i = 0; i < 4; ++i) {
        const int row0 = bm0 + wm + i * 16 + q * 4;
#pragma unroll
        for (int j = 0; j < 4; ++j) {
            const int col = bn0 + wn + j * 16 + lr;
            const float bv = bias[col];
#pragma unroll
            for (int qq = 0; qq < 4; ++qq)
                C[(size_t)(row0 + qq) * NDIM + col] = acc[i][j][qq] + bv;
        }
    }
}

extern "C" void kernel_launch(void* const* d_in, const int* in_sizes, int n_in,
                              void* d_out, int out_size, void* d_ws, size_t ws_size,
                              hipStream_t stream) {
    const float* x = (const float*)d_in[0];      // (4096, 4096) fp32
    const float* w = (const float*)d_in[1];      // (4096, 4096) fp32, OUT x IN
    const float* bias = (const float*)d_in[2];   // (4096,) fp32
    float* out = (float*)d_out;                  // (4096, 4096) fp32

    u16* xa = (u16*)d_ws;                        // 32 MiB bf16 x
    u16* wb = xa + (size_t)MDIM * KDIM;          // 32 MiB bf16 W

    // 4096*4096/4 = 4,194,304 float4 per matrix -> 16384 blocks each
    const int blocks_per_mat = (MDIM * KDIM) / 4 / 256;
    cvt2_f32_bf16<<<blocks_per_mat * 2, 256, 0, stream>>>(x, w, xa, wb);

    dim3 grid(NDIM / BN, MDIM / BM);             // 32 x 32
    gemm_bt_bias<<<grid, dim3(256), 0, stream>>>(xa, wb, bias, out);
}

// Round 3
// 291.517 us; speedup vs baseline: 1.1664x; 1.1664x over previous
//
#include <hip/hip_runtime.h>
#include <hip/hip_bf16.h>

typedef unsigned short u16;
typedef unsigned int u32;
typedef __attribute__((ext_vector_type(8))) short short8;
typedef __attribute__((ext_vector_type(4))) float floatx4;

#define MDIM 4096
#define NDIM 4096
#define KDIM 4096
#define BM 128
#define BN 128
#define BK 64

// ---------------- fp32 -> bf16 conversion, both matrices, one launch --------
__global__ __launch_bounds__(256) void cvt2_f32_bf16(const float* __restrict__ x,
                                                     const float* __restrict__ w,
                                                     u16* __restrict__ xa,
                                                     u16* __restrict__ wb) {
    const int half = gridDim.x >> 1;
    int b = blockIdx.x;
    const float* src = x;
    u16* dst = xa;
    if (b >= half) { src = w; dst = wb; b -= half; }
    const int i = b * 256 + threadIdx.x;           // float4 index
    float4 f = ((const float4*)src)[i];
    u32 ua = __float_as_uint(f.x), ub = __float_as_uint(f.y);
    u32 uc = __float_as_uint(f.z), ud = __float_as_uint(f.w);
    ushort4 o;                                     // RNE to bf16
    o.x = (u16)((ua + 0x7fffu + ((ua >> 16) & 1u)) >> 16);
    o.y = (u16)((ub + 0x7fffu + ((ub >> 16) & 1u)) >> 16);
    o.z = (u16)((uc + 0x7fffu + ((uc >> 16) & 1u)) >> 16);
    o.w = (u16)((ud + 0x7fffu + ((ud >> 16) & 1u)) >> 16);
    ((ushort4*)dst)[i] = o;
}

// ---------------- bf16 GEMM, C = A * B^T + bias ----------------
// BK=64: 2 barriers per 32 MFMA (vs per 16 at BK=32). LDS 32 KiB -> ~3 blk/CU.
// XOR-3 swizzle: row stride is 128 B (all rows bank-alias), so k-chunk c of
// row r is stored at LDS slot c^(r&7). Staging fetches global chunk
// (slot)^(r&7) -- still one 128 B segment per 8 lanes. Fragment reads then
// spread the 64 lanes over all 8 bank-nibbles (b128 floor, no 16-way pileup).
// Prefetch: stage k+1 AFTER the read-barrier (its vmcnt drain happens at the
// NEXT top-of-loop barrier, so 32 MFMAs overlap the load latency).
typedef const __attribute__((address_space(1))) void* gas_ptr;
typedef __attribute__((address_space(3))) void* lds_ptr;

__global__ __launch_bounds__(256, 3) void gemm_bt_bias(const u16* __restrict__ A,
                                                       const u16* __restrict__ B,
                                                       const float* __restrict__ bias,
                                                       float* __restrict__ C) {
    __shared__ u16 lA[BM * BK];  // 16 KiB
    __shared__ u16 lB[BN * BK];  // 16 KiB

    const int t = threadIdx.x;
    const int bm0 = blockIdx.y * BM;
    const int bn0 = blockIdx.x * BN;

    const int wave = t >> 6;
    const int lane = t & 63;
    const int wm = (wave & 1) * 64;
    const int wn = (wave >> 1) * 64;
    const int lr = lane & 15;          // m (A) / n (B) within 16
    const int q  = lane >> 4;          // k-quad 0..3

    floatx4 acc[4][4] = {};

    // staging: 4 stages per matrix; stage s, thread t -> linear idx = s*256+t,
    // row = idx>>3, slot = idx&7, fetch global chunk slot^(row&7).
    const u16* gA[4]; const u16* gB[4];
    u16* lAp[4]; u16* lBp[4];
#pragma unroll
    for (int s = 0; s < 4; ++s) {
        const int idx = s * 256 + t;
        const int row = idx >> 3;
        const int c = (idx & 7) ^ (row & 7);       // global k-chunk (8 elems)
        gA[s] = A + (size_t)(bm0 + row) * KDIM + c * 8;
        gB[s] = B + (size_t)(bn0 + row) * KDIM + c * 8;
        lAp[s] = &lA[(size_t)idx * 8];
        lBp[s] = &lB[(size_t)idx * 8];
    }

    // k0 = 0 stage
#pragma unroll
    for (int s = 0; s < 4; ++s) {
        __builtin_amdgcn_global_load_lds((gas_ptr)gA[s], (lds_ptr)lAp[s], 16, 0, 0);
        __builtin_amdgcn_global_load_lds((gas_ptr)gB[s], (lds_ptr)lBp[s], 16, 0, 0);
    }

    // fragment LDS element offsets (swizzled): row*64 + ((4*step+q)^(lr&7))*8
    const int lx = lr & 7;

    for (int k0 = 0; k0 < KDIM; k0 += BK) {
        __syncthreads();   // drains vmcnt(0): staging for k0 visible to all

        short8 af[4][2], bfr[4][2];
#pragma unroll
        for (int i = 0; i < 4; ++i) {
            const int row = wm + i * 16 + lr;
#pragma unroll
            for (int st = 0; st < 2; ++st)
                af[i][st] = *(const short8*)&lA[row * BK + (((st * 4 + q) ^ lx) * 8)];
        }
#pragma unroll
        for (int j = 0; j < 4; ++j) {
            const int row = wn + j * 16 + lr;
#pragma unroll
            for (int st = 0; st < 2; ++st)
                bfr[j][st] = *(const short8*)&lB[row * BK + (((st * 4 + q) ^ lx) * 8)];
        }

        __syncthreads();   // all waves' ds_reads done -> LDS reusable

        if (k0 + BK < KDIM) {
            const int ko = k0 + BK;
#pragma unroll
            for (int s = 0; s < 4; ++s) {
                __builtin_amdgcn_global_load_lds((gas_ptr)(gA[s] + ko), (lds_ptr)lAp[s], 16, 0, 0);
                __builtin_amdgcn_global_load_lds((gas_ptr)(gB[s] + ko), (lds_ptr)lBp[s], 16, 0, 0);
            }
        }

#pragma unroll
        for (int st = 0; st < 2; ++st)
#pragma unroll
            for (int i = 0; i < 4; ++i)
#pragma unroll
                for (int j = 0; j < 4; ++j)
                    acc[i][j] = __builtin_amdgcn_mfma_f32_16x16x32_bf16(af[i][st], bfr[j][st], acc[i][j], 0, 0, 0);
    }

    // epilogue: C/D layout col=lane&15, row=(lane>>4)*4+qq  [m89-verified]
#pragma unroll
    for (int i = 0; i < 4; ++i) {
        const int row0 = bm0 + wm + i * 16 + q * 4;
#pragma unroll
        for (int j = 0; j < 4; ++j) {
            const int col = bn0 + wn + j * 16 + lr;
            const float bv = bias[col];
#pragma unroll
            for (int qq = 0; qq < 4; ++qq)
                C[(size_t)(row0 + qq) * NDIM + col] = acc[i][j][qq] + bv;
        }
    }
}

extern "C" void kernel_launch(void* const* d_in, const int* in_sizes, int n_in,
                              void* d_out, int out_size, void* d_ws, size_t ws_size,
                              hipStream_t stream) {
    const float* x = (const float*)d_in[0];      // (4096, 4096) fp32
    const float* w = (const float*)d_in[1];      // (4096, 4096) fp32, OUT x IN
    const float* bias = (const float*)d_in[2];   // (4096,) fp32
    float* out = (float*)d_out;                  // (4096, 4096) fp32

    u16* xa = (u16*)d_ws;                        // 32 MiB bf16 x
    u16* wb = xa + (size_t)MDIM * KDIM;          // 32 MiB bf16 W

    const int blocks_per_mat = (MDIM * KDIM) / 4 / 256;   // 16384
    cvt2_f32_bf16<<<blocks_per_mat * 2, 256, 0, stream>>>(x, w, xa, wb);

    dim3 grid(NDIM / BN, MDIM / BM);             // 32 x 32
    gemm_bt_bias<<<grid, dim3(256), 0, stream>>>(xa, wb, bias, out);
}